// Round 13
// baseline (163.792 us; speedup 1.0000x reference)
//
#include <hip/hip_runtime.h>
#include <hip/hip_bf16.h>

#define B_SZ 1024
#define F_SZ 2048
#define NK   32
#define NCOL 256            // NK*KD
#define OUTF 2080           // F + NK
#define REP_K1 12           // instrumentation multipliers (deterministic recompute;
#define REP_K2 6            //  only last K2 rep does the real atomics)

typedef __attribute__((ext_vector_type(8))) short short8v;
typedef __attribute__((ext_vector_type(4))) float f32x4;

static __device__ __forceinline__ unsigned short f2bf(float v) {
  __hip_bfloat16 h = __float2bfloat16(v);   // RNE
  return reinterpret_cast<unsigned short&>(h);
}

// ---------------------------------------------------------------------------
// K1 (x REP_K1): role-split 384 blocks x 512 thr.  Same work as R12 per rep.
// ---------------------------------------------------------------------------
__global__ __launch_bounds__(512) void k1_gemm_copy(
    const float* __restrict__ x, const float* __restrict__ W,
    float* __restrict__ m, float* __restrict__ out) {
  __shared__ float red[8][16][64];   // 32 KB

  int bid = blockIdx.x;
  int t = threadIdx.x;

  if (bid >= 256) {
    const float4* x4 = reinterpret_cast<const float4*>(x);
    int base = (bid - 256) * 512 + t;
    for (int rep = 0; rep < REP_K1; ++rep) {
      if (base < B_SZ * NK)
        out[(size_t)(base >> 5) * OUTF + F_SZ + (base & 31)] = 0.f;
#pragma unroll
      for (int it = 0; it < 8; ++it) {
        int idx = base + it * 128 * 512;
        int i  = idx >> 9;
        int c4 = idx & 511;
        *reinterpret_cast<float4*>(&out[(size_t)i * OUTF + c4 * 4]) = x4[idx];
      }
    }
    return;
  }

  int mt = bid & 31, nt = bid >> 5;
  int i0 = mt * 32, n0 = nt * 32;
  int w = t >> 6, l = t & 63;
  int hi = l >> 4, r16 = l & 15;
  int hi8 = hi * 8;

  for (int rep = 0; rep < REP_K1; ++rep) {
    f32x4 acc[2][2];
#pragma unroll
    for (int mi = 0; mi < 2; ++mi)
#pragma unroll
      for (int ni = 0; ni < 2; ++ni) acc[mi][ni] = (f32x4)(0.f);

    for (int ks = 0; ks < 8; ++ks) {   // wave-private K chunk, no barriers
      int kc = w * 256 + ks * 32;

      short8v af[2];
#pragma unroll
      for (int mi = 0; mi < 2; ++mi) {
        const float* ap = &x[(size_t)(i0 + mi * 16 + r16) * F_SZ + kc + hi8];
        float4 v0 = *reinterpret_cast<const float4*>(ap);
        float4 v1 = *reinterpret_cast<const float4*>(ap + 4);
        af[mi][0] = (short)f2bf(v0.x); af[mi][1] = (short)f2bf(v0.y);
        af[mi][2] = (short)f2bf(v0.z); af[mi][3] = (short)f2bf(v0.w);
        af[mi][4] = (short)f2bf(v1.x); af[mi][5] = (short)f2bf(v1.y);
        af[mi][6] = (short)f2bf(v1.z); af[mi][7] = (short)f2bf(v1.w);
      }

      short8v bfr[2];
#pragma unroll
      for (int ni = 0; ni < 2; ++ni) {
        int n = n0 + ni * 16 + r16;
        float wv[8];
#pragma unroll
        for (int u = 0; u < 8; ++u)
          wv[u] = W[(size_t)(kc + hi8 + u) * NCOL + n];
#pragma unroll
        for (int u = 0; u < 8; ++u) bfr[ni][u] = (short)f2bf(wv[u]);
      }

#pragma unroll
      for (int mi = 0; mi < 2; ++mi)
#pragma unroll
        for (int ni = 0; ni < 2; ++ni)
          acc[mi][ni] = __builtin_amdgcn_mfma_f32_16x16x32_bf16(
              af[mi], bfr[ni], acc[mi][ni], 0, 0, 0);
    }

    __syncthreads();   // prior rep's red reads complete
#pragma unroll
    for (int mi = 0; mi < 2; ++mi)
#pragma unroll
      for (int ni = 0; ni < 2; ++ni)
#pragma unroll
        for (int r = 0; r < 4; ++r)
          red[w][mi * 8 + ni * 4 + r][l] = acc[mi][ni][r];
    __syncthreads();

#pragma unroll
    for (int s = 0; s < 2; ++s) {
      int slot = t + s * 512;
      int reg = slot >> 6, lane = slot & 63;
      float v = 0.f;
#pragma unroll
      for (int ww = 0; ww < 8; ++ww) v += red[ww][reg][lane];
      int mi = reg >> 3, ni = (reg >> 2) & 1, r = reg & 3;
      int row = i0 + mi * 16 + (lane >> 4) * 4 + r;   // C/D: col=lane&15, row=(lane>>4)*4+reg
      int col = n0 + ni * 16 + (lane & 15);
      m[(size_t)row * NCOL + col] = v;
    }
  }
}

// ---------------------------------------------------------------------------
// K2 (x REP_K2): symmetric pairwise (R12 structure).  Reps 0..REP-2 store to
// Pscr (keeps compute live, deterministic); last rep does the real atomics.
// ---------------------------------------------------------------------------
__global__ __launch_bounds__(512) void k2_sym_pairwise(
    const float* __restrict__ m, float* __restrict__ out,
    float* __restrict__ Pscr) {
  __shared__ float redJ[8][32][32];   // 32 KB

  int b = blockIdx.x;
  int a = 0, rem = b;
  while (rem >= 32 - a) { rem -= 32 - a; ++a; }   // triangular decode
  int c = a + rem;
  bool offd = (a != c);

  int t = threadIdx.x;
  int k = t & 31, g = t >> 5;        // g 0..15
  int w = t >> 6;                    // wave 0..7
  int ia = a * 32 + g * 2;
  float* myP = &Pscr[(size_t)b * 2048];

  const float4* mv = reinterpret_cast<const float4*>(m);

  for (int rep = 0; rep < REP_K2; ++rep) {
    bool real = (rep == REP_K2 - 1);

    float4 A00 = mv[(size_t)ia * 64 + k * 2];
    float4 A01 = mv[(size_t)ia * 64 + k * 2 + 1];
    float4 A10 = mv[(size_t)(ia + 1) * 64 + k * 2];
    float4 A11 = mv[(size_t)(ia + 1) * 64 + k * 2 + 1];

    float accI0 = 0.f, accI1 = 0.f;
    float accJr[32];
#pragma unroll
    for (int jj = 0; jj < 32; ++jj) {
      int j = c * 32 + jj;
      float4 C0 = mv[(size_t)j * 64 + k * 2];
      float4 C1 = mv[(size_t)j * 64 + k * 2 + 1];
      float s0 = fabsf(A00.x - C0.x) + fabsf(A00.y - C0.y) +
                 fabsf(A00.z - C0.z) + fabsf(A00.w - C0.w) +
                 fabsf(A01.x - C1.x) + fabsf(A01.y - C1.y) +
                 fabsf(A01.z - C1.z) + fabsf(A01.w - C1.w);
      float s1 = fabsf(A10.x - C0.x) + fabsf(A10.y - C0.y) +
                 fabsf(A10.z - C0.z) + fabsf(A10.w - C0.w) +
                 fabsf(A11.x - C1.x) + fabsf(A11.y - C1.y) +
                 fabsf(A11.z - C1.z) + fabsf(A11.w - C1.w);
      float e0 = __expf(-s0);
      float e1 = __expf(-s1);
      accI0 += e0;
      accI1 += e1;
      accJr[jj] = e0 + e1;           // register, compile-time index
    }

    if (real) {
      atomicAdd(&out[(size_t)ia * OUTF + F_SZ + k], accI0);
      atomicAdd(&out[(size_t)(ia + 1) * OUTF + F_SZ + k], accI1);
    } else {
      myP[t] = accI0;                // deterministic scratch; keeps compute live
      myP[512 + t] = accI1;
    }

    if (offd) {
#pragma unroll
      for (int jj = 0; jj < 32; ++jj)
        accJr[jj] += __shfl_xor(accJr[jj], 32);
      if ((t & 63) < 32) {
#pragma unroll
        for (int jj = 0; jj < 32; ++jj)
          redJ[w][jj][k] = accJr[jj];
      }
      __syncthreads();
#pragma unroll
      for (int s = 0; s < 2; ++s) {
        int slot = t + s * 512;
        int j = slot >> 5, kk = slot & 31;
        float v = 0.f;
#pragma unroll
        for (int ww = 0; ww < 8; ++ww) v += redJ[ww][j][kk];
        if (real) atomicAdd(&out[(size_t)(c * 32 + j) * OUTF + F_SZ + kk], v);
        else      myP[1024 + slot] = v;
      }
      __syncthreads();               // redJ reuse across reps
    }
  }
}

extern "C" void kernel_launch(void* const* d_in, const int* in_sizes, int n_in,
                              void* d_out, int out_size, void* d_ws, size_t ws_size,
                              hipStream_t stream) {
  const float* x = (const float*)d_in[0];
  const float* W = (const float*)d_in[1];
  float* out = (float*)d_out;
  char* ws = (char*)d_ws;

  const size_t MB = 1u << 20;
  float* m    = (float*)ws;             // 1 MB
  float* Pscr = (float*)(ws + MB);      // 4.3 MB scratch for instrumentation reps

  k1_gemm_copy<<<dim3(384), 512, 0, stream>>>(x, W, m, out);
  k2_sym_pairwise<<<dim3(528), 512, 0, stream>>>(m, out, Pscr);
}

// Round 14
// 45.298 us; speedup vs baseline: 3.6159x; 3.6159x over previous
//
#include <hip/hip_runtime.h>
#include <hip/hip_bf16.h>

#define B_SZ 1024
#define F_SZ 2048
#define NK   32
#define NCOL 256            // NK*KD
#define OUTF 2080           // F + NK

typedef __attribute__((ext_vector_type(8))) short short8v;
typedef __attribute__((ext_vector_type(4))) float f32x4;

static __device__ __forceinline__ unsigned short f2bf(float v) {
  __hip_bfloat16 h = __float2bfloat16(v);   // RNE
  return reinterpret_cast<unsigned short&>(h);
}

// ---------------------------------------------------------------------------
// K1: parity-interleaved roles, 512 blocks x 512 thr (2 blocks/CU everywhere).
//   even bid : GEMM tile (bid>>1): 32x32 output tile, 8 waves split K,
//              direct global->reg loads, barrier-free (R9-proven, ~2.6 us).
//   odd bid  : copy slice (bid>>1): x rows -> out[:, 0:2048] + zero mb cols.
// R13 lesson: role blocks must round-robin onto ALL CUs, not occupy a
// contiguous bid range (which parks them on half the chip).
// ---------------------------------------------------------------------------
__global__ __launch_bounds__(512) void k1_gemm_copy(
    const float* __restrict__ x, const float* __restrict__ W,
    float* __restrict__ m, float* __restrict__ out) {
  __shared__ float red[8][16][64];   // 32 KB (GEMM blocks only)

  int bid = blockIdx.x;
  int t = threadIdx.x;

  if (bid & 1) {
    // ---------------- copy role: slice cb of 256 ----------------
    int cb = bid >> 1;
    const float4* x4 = reinterpret_cast<const float4*>(x);
    int zidx = cb * 512 + t;
    if (zidx < B_SZ * NK)      // zero out[:, 2048:2080] for K2's atomics
      out[(size_t)(zidx >> 5) * OUTF + F_SZ + (zidx & 31)] = 0.f;
    int idx = cb * 2048 + t;
#pragma unroll
    for (int it = 0; it < 4; ++it, idx += 512) {
      int i  = idx >> 9;          // 512 float4 per x row
      int c4 = idx & 511;
      *reinterpret_cast<float4*>(&out[(size_t)i * OUTF + c4 * 4]) = x4[idx];
    }
    return;
  }

  // ---------------- GEMM role: tile gt of 256 ----------------
  int gt = bid >> 1;
  int mt = gt & 31, nt = gt >> 5;
  int i0 = mt * 32, n0 = nt * 32;
  int w = t >> 6, l = t & 63;
  int hi = l >> 4, r16 = l & 15;
  int hi8 = hi * 8;

  f32x4 acc[2][2];
#pragma unroll
  for (int mi = 0; mi < 2; ++mi)
#pragma unroll
    for (int ni = 0; ni < 2; ++ni) acc[mi][ni] = (f32x4)(0.f);

  for (int ks = 0; ks < 8; ++ks) {   // wave-private K chunk, no barriers
    int kc = w * 256 + ks * 32;

    short8v af[2];
#pragma unroll
    for (int mi = 0; mi < 2; ++mi) {
      const float* ap = &x[(size_t)(i0 + mi * 16 + r16) * F_SZ + kc + hi8];
      float4 v0 = *reinterpret_cast<const float4*>(ap);
      float4 v1 = *reinterpret_cast<const float4*>(ap + 4);
      af[mi][0] = (short)f2bf(v0.x); af[mi][1] = (short)f2bf(v0.y);
      af[mi][2] = (short)f2bf(v0.z); af[mi][3] = (short)f2bf(v0.w);
      af[mi][4] = (short)f2bf(v1.x); af[mi][5] = (short)f2bf(v1.y);
      af[mi][6] = (short)f2bf(v1.z); af[mi][7] = (short)f2bf(v1.w);
    }

    short8v bfr[2];
#pragma unroll
    for (int ni = 0; ni < 2; ++ni) {
      int n = n0 + ni * 16 + r16;
      float wv[8];
#pragma unroll
      for (int u = 0; u < 8; ++u)      // 4 cache lines / instr (4 k-rows x 64B)
        wv[u] = W[(size_t)(kc + hi8 + u) * NCOL + n];
#pragma unroll
      for (int u = 0; u < 8; ++u) bfr[ni][u] = (short)f2bf(wv[u]);
    }

#pragma unroll
    for (int mi = 0; mi < 2; ++mi)
#pragma unroll
      for (int ni = 0; ni < 2; ++ni)
        acc[mi][ni] = __builtin_amdgcn_mfma_f32_16x16x32_bf16(
            af[mi], bfr[ni], acc[mi][ni], 0, 0, 0);
  }

#pragma unroll
  for (int mi = 0; mi < 2; ++mi)
#pragma unroll
    for (int ni = 0; ni < 2; ++ni)
#pragma unroll
      for (int r = 0; r < 4; ++r)
        red[w][mi * 8 + ni * 4 + r][l] = acc[mi][ni][r];
  __syncthreads();

#pragma unroll
  for (int s = 0; s < 2; ++s) {
    int slot = t + s * 512;            // 1024 slots = 16 regs x 64 lanes
    int reg = slot >> 6, lane = slot & 63;
    float v = 0.f;
#pragma unroll
    for (int ww = 0; ww < 8; ++ww) v += red[ww][reg][lane];
    int mi = reg >> 3, ni = (reg >> 2) & 1, r = reg & 3;
    int row = i0 + mi * 16 + (lane >> 4) * 4 + r;   // C/D: col=lane&15, row=(lane>>4)*4+reg
    int col = n0 + ni * 16 + (lane & 15);
    m[(size_t)row * NCOL + col] = v;
  }
}

// ---------------------------------------------------------------------------
// K2: symmetric pairwise (R12-proven, ~4 us).  528 blocks x 512 thr.
// Tile-pair (a,c); thread (k=t&31, g=t>>5) owns i-rows {a*32+2g, +1};
// coalesced j-loop (half-wave reads one m-row, L1 broadcast); j-side in
// registers (full unroll); epilogue shfl_xor(32) + LDS 8-way + atomicAdd.
// ---------------------------------------------------------------------------
__global__ __launch_bounds__(512) void k2_sym_pairwise(
    const float* __restrict__ m, float* __restrict__ out) {
  __shared__ float redJ[8][32][32];   // 32 KB

  int b = blockIdx.x;
  int a = 0, rem = b;
  while (rem >= 32 - a) { rem -= 32 - a; ++a; }   // triangular decode
  int c = a + rem;
  bool offd = (a != c);

  int t = threadIdx.x;
  int k = t & 31, g = t >> 5;        // g 0..15
  int w = t >> 6;                    // wave 0..7
  int ia = a * 32 + g * 2;

  const float4* mv = reinterpret_cast<const float4*>(m);  // m[i][c4]: idx = i*64 + c4
  float4 A00 = mv[(size_t)ia * 64 + k * 2];
  float4 A01 = mv[(size_t)ia * 64 + k * 2 + 1];
  float4 A10 = mv[(size_t)(ia + 1) * 64 + k * 2];
  float4 A11 = mv[(size_t)(ia + 1) * 64 + k * 2 + 1];

  float accI0 = 0.f, accI1 = 0.f;
  float accJr[32];
#pragma unroll
  for (int jj = 0; jj < 32; ++jj) {
    int j = c * 32 + jj;
    float4 C0 = mv[(size_t)j * 64 + k * 2];
    float4 C1 = mv[(size_t)j * 64 + k * 2 + 1];
    float s0 = fabsf(A00.x - C0.x) + fabsf(A00.y - C0.y) +
               fabsf(A00.z - C0.z) + fabsf(A00.w - C0.w) +
               fabsf(A01.x - C1.x) + fabsf(A01.y - C1.y) +
               fabsf(A01.z - C1.z) + fabsf(A01.w - C1.w);
    float s1 = fabsf(A10.x - C0.x) + fabsf(A10.y - C0.y) +
               fabsf(A10.z - C0.z) + fabsf(A10.w - C0.w) +
               fabsf(A11.x - C1.x) + fabsf(A11.y - C1.y) +
               fabsf(A11.z - C1.z) + fabsf(A11.w - C1.w);
    float e0 = __expf(-s0);
    float e1 = __expf(-s1);
    accI0 += e0;
    accI1 += e1;
    accJr[jj] = e0 + e1;             // register, compile-time index
  }

  // i-side: unique owner per (row, k) -> device-scope atomicAdd into out
  atomicAdd(&out[(size_t)ia * OUTF + F_SZ + k], accI0);
  atomicAdd(&out[(size_t)(ia + 1) * OUTF + F_SZ + k], accI1);

  if (offd) {
    // combine the wave's two g's: lanes l and l^32 share k
#pragma unroll
    for (int jj = 0; jj < 32; ++jj)
      accJr[jj] += __shfl_xor(accJr[jj], 32);
    if ((t & 63) < 32) {             // lanes 0..31 hold the pair sums
#pragma unroll
      for (int jj = 0; jj < 32; ++jj)
        redJ[w][jj][k] = accJr[jj];  // banks = k: conflict-free
    }
    __syncthreads();
#pragma unroll
    for (int s = 0; s < 2; ++s) {
      int slot = t + s * 512;        // 1024 slots = 32 j x 32 k
      int j = slot >> 5, kk = slot & 31;
      float v = 0.f;
#pragma unroll
      for (int ww = 0; ww < 8; ++ww) v += redJ[ww][j][kk];
      atomicAdd(&out[(size_t)(c * 32 + j) * OUTF + F_SZ + kk], v);
    }
  }
}

extern "C" void kernel_launch(void* const* d_in, const int* in_sizes, int n_in,
                              void* d_out, int out_size, void* d_ws, size_t ws_size,
                              hipStream_t stream) {
  const float* x = (const float*)d_in[0];
  const float* W = (const float*)d_in[1];
  float* out = (float*)d_out;
  float* m = (float*)d_ws;    // 1 MB

  k1_gemm_copy<<<dim3(512), 512, 0, stream>>>(x, W, m, out);
  k2_sym_pairwise<<<dim3(528), 512, 0, stream>>>(m, out);
}

// Round 15
// 37.829 us; speedup vs baseline: 4.3298x; 1.1974x over previous
//
#include <hip/hip_runtime.h>
#include <hip/hip_bf16.h>

#define B_SZ 1024
#define F_SZ 2048
#define NK   32
#define NCOL 256            // NK*KD
#define OUTF 2080           // F + NK

typedef __attribute__((ext_vector_type(8))) short short8v;
typedef __attribute__((ext_vector_type(4))) float f32x4;

static __device__ __forceinline__ unsigned short f2bf(float v) {
  __hip_bfloat16 h = __float2bfloat16(v);   // RNE
  return reinterpret_cast<unsigned short&>(h);
}

// ---------------------------------------------------------------------------
// K1: FUSED roles, 256 blocks x 512 thr (1 block/CU; mapping-independent).
// Each block does ALL of:
//   (a) zero its 128 floats of out[:, 2048:2080]  (K2 atomics need 0 base)
//   (b) copy its contiguous 4-row x slice -> out[:, 0:2048] (fire-and-forget)
//   (c) GEMM tile bid: 32x32 output, 8 waves split K, direct global->reg,
//       barrier-free (R9-proven).  m = x.W  bf16 MFMA.
// R14 lesson: bid-range/parity role splits land on disjoint XCD sets
// (bid&7 = XCD); fusing roles per-block is robust to any dispatch mapping.
// Copy (HBM-bound, 33MB @ 6.3TB/s ~ 5.3us full chip) hides GEMM (~3us).
// ---------------------------------------------------------------------------
__global__ __launch_bounds__(512) void k1_fused(
    const float* __restrict__ x, const float* __restrict__ W,
    float* __restrict__ m, float* __restrict__ out) {
  __shared__ float red[8][16][64];   // 32 KB

  int bid = blockIdx.x;   // 0..255
  int t = threadIdx.x;

  // ---- (a) zero mb columns: 256 blocks x 128 = 32768 floats ----
  if (t < 128) {
    int zi = bid * 128 + t;
    out[(size_t)(zi >> 5) * OUTF + F_SZ + (zi & 31)] = 0.f;
  }

  // ---- (b) copy slice: 2048 float4 (4 x-rows), coalesced ----
  {
    const float4* x4 = reinterpret_cast<const float4*>(x);
    int idx = bid * 2048 + t;
#pragma unroll
    for (int it = 0; it < 4; ++it, idx += 512) {
      int i  = idx >> 9;          // 512 float4 per x row
      int c4 = idx & 511;
      *reinterpret_cast<float4*>(&out[(size_t)i * OUTF + c4 * 4]) = x4[idx];
    }
  }

  // ---- (c) GEMM tile ----
  int mt = bid & 31, nt = bid >> 5;
  int i0 = mt * 32, n0 = nt * 32;
  int w = t >> 6, l = t & 63;
  int hi = l >> 4, r16 = l & 15;
  int hi8 = hi * 8;

  f32x4 acc[2][2];
#pragma unroll
  for (int mi = 0; mi < 2; ++mi)
#pragma unroll
    for (int ni = 0; ni < 2; ++ni) acc[mi][ni] = (f32x4)(0.f);

  for (int ks = 0; ks < 8; ++ks) {   // wave-private K chunk, no barriers
    int kc = w * 256 + ks * 32;

    short8v af[2];
#pragma unroll
    for (int mi = 0; mi < 2; ++mi) {
      const float* ap = &x[(size_t)(i0 + mi * 16 + r16) * F_SZ + kc + hi8];
      float4 v0 = *reinterpret_cast<const float4*>(ap);
      float4 v1 = *reinterpret_cast<const float4*>(ap + 4);
      af[mi][0] = (short)f2bf(v0.x); af[mi][1] = (short)f2bf(v0.y);
      af[mi][2] = (short)f2bf(v0.z); af[mi][3] = (short)f2bf(v0.w);
      af[mi][4] = (short)f2bf(v1.x); af[mi][5] = (short)f2bf(v1.y);
      af[mi][6] = (short)f2bf(v1.z); af[mi][7] = (short)f2bf(v1.w);
    }

    short8v bfr[2];
#pragma unroll
    for (int ni = 0; ni < 2; ++ni) {
      int n = n0 + ni * 16 + r16;
      float wv[8];
#pragma unroll
      for (int u = 0; u < 8; ++u)      // 4 cache lines / instr (4 k-rows x 64B)
        wv[u] = W[(size_t)(kc + hi8 + u) * NCOL + n];
#pragma unroll
      for (int u = 0; u < 8; ++u) bfr[ni][u] = (short)f2bf(wv[u]);
    }

#pragma unroll
    for (int mi = 0; mi < 2; ++mi)
#pragma unroll
      for (int ni = 0; ni < 2; ++ni)
        acc[mi][ni] = __builtin_amdgcn_mfma_f32_16x16x32_bf16(
            af[mi], bfr[ni], acc[mi][ni], 0, 0, 0);
  }

#pragma unroll
  for (int mi = 0; mi < 2; ++mi)
#pragma unroll
    for (int ni = 0; ni < 2; ++ni)
#pragma unroll
      for (int r = 0; r < 4; ++r)
        red[w][mi * 8 + ni * 4 + r][l] = acc[mi][ni][r];
  __syncthreads();

#pragma unroll
  for (int s = 0; s < 2; ++s) {
    int slot = t + s * 512;            // 1024 slots = 16 regs x 64 lanes
    int reg = slot >> 6, lane = slot & 63;
    float v = 0.f;
#pragma unroll
    for (int ww = 0; ww < 8; ++ww) v += red[ww][reg][lane];
    int mi = reg >> 3, ni = (reg >> 2) & 1, r = reg & 3;
    int row = i0 + mi * 16 + (lane >> 4) * 4 + r;   // C/D: col=lane&15, row=(lane>>4)*4+reg
    int col = n0 + ni * 16 + (lane & 15);
    m[(size_t)row * NCOL + col] = v;
  }
}

// ---------------------------------------------------------------------------
// K2: symmetric pairwise (R12-proven, ~3.5 us).  528 blocks x 512 thr.
// Tile-pair (a,c); thread (k=t&31, g=t>>5) owns i-rows {a*32+2g, +1};
// coalesced j-loop (half-wave reads one m-row, L1 broadcast); j-side in
// registers (full unroll); epilogue shfl_xor(32) + LDS 8-way + atomicAdd.
// ---------------------------------------------------------------------------
__global__ __launch_bounds__(512) void k2_sym_pairwise(
    const float* __restrict__ m, float* __restrict__ out) {
  __shared__ float redJ[8][32][32];   // 32 KB

  int b = blockIdx.x;
  int a = 0, rem = b;
  while (rem >= 32 - a) { rem -= 32 - a; ++a; }   // triangular decode
  int c = a + rem;
  bool offd = (a != c);

  int t = threadIdx.x;
  int k = t & 31, g = t >> 5;        // g 0..15
  int w = t >> 6;                    // wave 0..7
  int ia = a * 32 + g * 2;

  const float4* mv = reinterpret_cast<const float4*>(m);  // m[i][c4]: idx = i*64 + c4
  float4 A00 = mv[(size_t)ia * 64 + k * 2];
  float4 A01 = mv[(size_t)ia * 64 + k * 2 + 1];
  float4 A10 = mv[(size_t)(ia + 1) * 64 + k * 2];
  float4 A11 = mv[(size_t)(ia + 1) * 64 + k * 2 + 1];

  float accI0 = 0.f, accI1 = 0.f;
  float accJr[32];
#pragma unroll
  for (int jj = 0; jj < 32; ++jj) {
    int j = c * 32 + jj;
    float4 C0 = mv[(size_t)j * 64 + k * 2];
    float4 C1 = mv[(size_t)j * 64 + k * 2 + 1];
    float s0 = fabsf(A00.x - C0.x) + fabsf(A00.y - C0.y) +
               fabsf(A00.z - C0.z) + fabsf(A00.w - C0.w) +
               fabsf(A01.x - C1.x) + fabsf(A01.y - C1.y) +
               fabsf(A01.z - C1.z) + fabsf(A01.w - C1.w);
    float s1 = fabsf(A10.x - C0.x) + fabsf(A10.y - C0.y) +
               fabsf(A10.z - C0.z) + fabsf(A10.w - C0.w) +
               fabsf(A11.x - C1.x) + fabsf(A11.y - C1.y) +
               fabsf(A11.z - C1.z) + fabsf(A11.w - C1.w);
    float e0 = __expf(-s0);
    float e1 = __expf(-s1);
    accI0 += e0;
    accI1 += e1;
    accJr[jj] = e0 + e1;             // register, compile-time index
  }

  // i-side: unique owner per (row, k) -> device-scope atomicAdd into out
  atomicAdd(&out[(size_t)ia * OUTF + F_SZ + k], accI0);
  atomicAdd(&out[(size_t)(ia + 1) * OUTF + F_SZ + k], accI1);

  if (offd) {
    // combine the wave's two g's: lanes l and l^32 share k
#pragma unroll
    for (int jj = 0; jj < 32; ++jj)
      accJr[jj] += __shfl_xor(accJr[jj], 32);
    if ((t & 63) < 32) {             // lanes 0..31 hold the pair sums
#pragma unroll
      for (int jj = 0; jj < 32; ++jj)
        redJ[w][jj][k] = accJr[jj];  // banks = k: conflict-free
    }
    __syncthreads();
#pragma unroll
    for (int s = 0; s < 2; ++s) {
      int slot = t + s * 512;        // 1024 slots = 32 j x 32 k
      int j = slot >> 5, kk = slot & 31;
      float v = 0.f;
#pragma unroll
      for (int ww = 0; ww < 8; ++ww) v += redJ[ww][j][kk];
      atomicAdd(&out[(size_t)(c * 32 + j) * OUTF + F_SZ + kk], v);
    }
  }
}

extern "C" void kernel_launch(void* const* d_in, const int* in_sizes, int n_in,
                              void* d_out, int out_size, void* d_ws, size_t ws_size,
                              hipStream_t stream) {
  const float* x = (const float*)d_in[0];
  const float* W = (const float*)d_in[1];
  float* out = (float*)d_out;
  float* m = (float*)d_ws;    // 1 MB

  k1_fused<<<dim3(256), 512, 0, stream>>>(x, W, m, out);
  k2_sym_pairwise<<<dim3(528), 512, 0, stream>>>(m, out);
}